// Round 1
// baseline (219.036 us; speedup 1.0000x reference)
//
#include <hip/hip_runtime.h>
#include <stdint.h>

#define DIM   384
#define NH    6
#define SEQ   4096
#define MTOT  (2*SEQ)

typedef __bf16 bf16x8 __attribute__((ext_vector_type(8)));
typedef float  f32x4  __attribute__((ext_vector_type(4)));
typedef unsigned short u16;
typedef u16 u16x4 __attribute__((ext_vector_type(4)));
typedef u16 u16x8 __attribute__((ext_vector_type(8)));

__device__ __forceinline__ u16 f2b(float f) {
  uint32_t u = __builtin_bit_cast(uint32_t, f);
  u += 0x7fffu + ((u >> 16) & 1u);
  return (u16)(u >> 16);
}

#define GLDS16(gp, lp) \
  __builtin_amdgcn_global_load_lds((const __attribute__((address_space(1))) void*)(gp), \
                                   (__attribute__((address_space(3))) void*)(lp), 16, 0, 0)

// ---------------- fp32 -> bf16 convert, 8 elems/thread ----------------
__global__ void conv_bf16_kernel(const float* __restrict__ in, u16* __restrict__ out, int n8) {
  int i = blockIdx.x * 256 + threadIdx.x;
  if (i >= n8) return;
  float4 a = ((const float4*)in)[2*i];
  float4 b = ((const float4*)in)[2*i+1];
  u16x8 r;
  r[0]=f2b(a.x); r[1]=f2b(a.y); r[2]=f2b(a.z); r[3]=f2b(a.w);
  r[4]=f2b(b.x); r[5]=f2b(b.y); r[6]=f2b(b.z); r[7]=f2b(b.w);
  ((u16x8*)out)[i] = r;
}

// ---------------- GEMM: C[m][f] = sum_c A[m][c]*Bw[f][c] + bias[f] ----------------
// EPI==0: qkv epilogue (scatter Q scaled, K, V transposed). EPI==1: proj -> fp32 Out.
// 128x128 tile, BK=64, 4 waves (2x2), 4x4 16x16x32 fragments per wave.
template<int EPI>
__global__ __launch_bounds__(256) void gemm_bt_kernel(
    const u16* __restrict__ A,      // [M][384] bf16 K-contig
    const u16* __restrict__ Bw,     // [F][384] bf16 K-contig
    const float* __restrict__ bias, // [F]
    u16* __restrict__ Qb, u16* __restrict__ Kb, u16* __restrict__ Vt,
    float* __restrict__ Out)
{
  __shared__ u16 As[128*64];
  __shared__ u16 Bs[128*64];
  const int tid = threadIdx.x;
  const int wid = tid >> 6, lane = tid & 63;
  const int lr = lane & 15, lg = lane >> 4;
  const int m0 = blockIdx.x * 128;
  const int f0 = blockIdx.y * 128;
  const int wm = (wid >> 1) * 64, wn = (wid & 1) * 64;
  const f32x4 z4 = {0.f, 0.f, 0.f, 0.f};
  f32x4 acc[4][4];
  #pragma unroll
  for (int i = 0; i < 4; ++i)
    #pragma unroll
    for (int j = 0; j < 4; ++j) acc[i][j] = z4;

  for (int k0 = 0; k0 < 384; k0 += 64) {
    __syncthreads();
    // stage A,B tiles [128 rows][64 k] bf16, XOR-swizzled via pre-swizzled global src
    #pragma unroll
    for (int i = 0; i < 4; ++i) {
      const int wb  = i*4096 + wid*1024;      // wave-uniform LDS byte base
      const int ob  = wb + lane*16;           // this lane's linear LDS byte
      const int row = ob >> 7;                // 128B per row
      const int lch = ((ob >> 4) & 7) ^ (row & 7);
      GLDS16(A  + (size_t)(m0+row)*384 + k0 + lch*8, As + wb/2);
      GLDS16(Bw + (size_t)(f0+row)*384 + k0 + lch*8, Bs + wb/2);
    }
    __syncthreads();
    #pragma unroll
    for (int ks = 0; ks < 2; ++ks) {
      bf16x8 af[4], bfr[4];
      #pragma unroll
      for (int mi = 0; mi < 4; ++mi) {
        int r = wm + mi*16 + lr;
        af[mi] = *(const bf16x8*)(As + (r*128 + ((ks*64 + lg*16) ^ ((r&7)<<4)))/2);
      }
      #pragma unroll
      for (int ni = 0; ni < 4; ++ni) {
        int r = wn + ni*16 + lr;
        bfr[ni] = *(const bf16x8*)(Bs + (r*128 + ((ks*64 + lg*16) ^ ((r&7)<<4)))/2);
      }
      #pragma unroll
      for (int mi = 0; mi < 4; ++mi)
        #pragma unroll
        for (int ni = 0; ni < 4; ++ni)
          acc[mi][ni] = __builtin_amdgcn_mfma_f32_16x16x32_bf16(af[mi], bfr[ni], acc[mi][ni], 0, 0, 0);
    }
  }

  if (EPI == 0) {
    const int which = f0 / 384;               // uniform per block (384 = 3*128)
    #pragma unroll
    for (int ni = 0; ni < 4; ++ni) {
      const int f   = f0 + wn + ni*16 + lr;   // C col = lane&15
      const float bv = bias[f];
      const int rem = f - which*384;
      const int h = rem >> 6, d = rem & 63;
      #pragma unroll
      for (int mi = 0; mi < 4; ++mi) {
        const int m = m0 + wm + mi*16 + lg*4; // C row = 4*(lane>>4)+j
        const int b = m >> 12, n = m & 4095;
        const size_t bh = (size_t)(b*NH + h);
        if (which == 0) {
          #pragma unroll
          for (int j = 0; j < 4; ++j)
            Qb[(bh*SEQ + n + j)*64 + d] = f2b((acc[mi][ni][j] + bv) * 0.125f);
        } else if (which == 1) {
          #pragma unroll
          for (int j = 0; j < 4; ++j)
            Kb[(bh*SEQ + n + j)*64 + d] = f2b(acc[mi][ni][j] + bv);
        } else {
          u16x4 pk;
          #pragma unroll
          for (int j = 0; j < 4; ++j) pk[j] = f2b(acc[mi][ni][j] + bv);
          *(u16x4*)(Vt + (bh*64 + d)*SEQ + n) = pk;   // V transposed [bh][d][n]
        }
      }
    }
  } else {
    #pragma unroll
    for (int ni = 0; ni < 4; ++ni) {
      const int f = f0 + wn + ni*16 + lr;
      const float bv = bias[f];
      #pragma unroll
      for (int mi = 0; mi < 4; ++mi) {
        const int m = m0 + wm + mi*16 + lg*4;
        #pragma unroll
        for (int j = 0; j < 4; ++j)
          Out[(size_t)(m+j)*DIM + f] = acc[mi][ni][j] + bv;
      }
    }
  }
}

// ---------------- flash attention ----------------
// grid (SEQ/64, 12). Block: 4 waves x 16 q-rows. K tile [64 keys][64 d],
// V tile [64 d][64 keys] (from pre-transposed Vt), both XOR-swizzled.
__global__ __launch_bounds__(256) void attn_kernel(
    const u16* __restrict__ Qb, const u16* __restrict__ Kb, const u16* __restrict__ Vt,
    u16* __restrict__ AO)
{
  __shared__ u16 Ks[64*64];
  __shared__ u16 Vs[64*64];
  __shared__ u16 Ps[4][16*64];
  const int tid = threadIdx.x;
  const int wid = tid >> 6, lane = tid & 63;
  const int lr = lane & 15, lg = lane >> 4;
  const int q0 = blockIdx.x * 64;
  const int bh = blockIdx.y;
  const u16* Qp = Qb + (size_t)bh*SEQ*64;
  const u16* Kp = Kb + (size_t)bh*SEQ*64;
  const u16* Vp = Vt + (size_t)bh*64*SEQ;

  // Q A-fragments in registers for the whole kernel (rows pre-scaled by 1/8)
  bf16x8 qf[2];
  {
    const u16* qr = Qp + (size_t)(q0 + wid*16 + lr)*64 + lg*8;
    qf[0] = *(const bf16x8*)(qr);
    qf[1] = *(const bf16x8*)(qr + 32);
  }
  const f32x4 z4 = {0.f,0.f,0.f,0.f};
  f32x4 o[4] = {z4, z4, z4, z4};
  float mrow[4] = {-1e30f,-1e30f,-1e30f,-1e30f};
  float lrow[4] = {0.f,0.f,0.f,0.f};

  for (int kt = 0; kt < SEQ/64; ++kt) {
    const int key0 = kt * 64;
    __syncthreads();                       // protect K/V LDS from prior readers
    #pragma unroll
    for (int i = 0; i < 2; ++i) {
      const int wb  = i*4096 + wid*1024;
      const int ob  = wb + lane*16;
      const int row = ob >> 7;
      const int lch = ((ob >> 4) & 7) ^ (row & 7);
      GLDS16(Kp + (size_t)(key0+row)*64 + lch*8, Ks + wb/2);  // row = key
      GLDS16(Vp + (size_t)row*SEQ + key0 + lch*8, Vs + wb/2); // row = d
    }
    __syncthreads();                       // compiler drains vmcnt before barrier

    // S = Q·K^T  (16 q-rows x 64 keys per wave)
    f32x4 s[4] = {z4, z4, z4, z4};
    #pragma unroll
    for (int ks = 0; ks < 2; ++ks) {
      #pragma unroll
      for (int ni = 0; ni < 4; ++ni) {
        const int key = ni*16 + lr;
        bf16x8 kf = *(const bf16x8*)(Ks + (key*128 + ((ks*64 + lg*16) ^ ((key&7)<<4)))/2);
        s[ni] = __builtin_amdgcn_mfma_f32_16x16x32_bf16(qf[ks], kf, s[ni], 0, 0, 0);
      }
    }

    // online softmax: row r = 4*lg + j lives in 16-lane group, reg j
    float alpha[4];
    #pragma unroll
    for (int j = 0; j < 4; ++j) {
      float v = fmaxf(fmaxf(s[0][j], s[1][j]), fmaxf(s[2][j], s[3][j]));
      v = fmaxf(v, __shfl_xor(v, 1));
      v = fmaxf(v, __shfl_xor(v, 2));
      v = fmaxf(v, __shfl_xor(v, 4));
      v = fmaxf(v, __shfl_xor(v, 8));
      float mnew = fmaxf(mrow[j], v);
      alpha[j] = __expf(mrow[j] - mnew);
      mrow[j] = mnew;
    }
    float rs[4] = {0.f,0.f,0.f,0.f};
    #pragma unroll
    for (int ni = 0; ni < 4; ++ni)
      #pragma unroll
      for (int j = 0; j < 4; ++j) {
        float p = __expf(s[ni][j] - mrow[j]);
        s[ni][j] = p;
        rs[j] += p;
      }
    #pragma unroll
    for (int j = 0; j < 4; ++j) {
      float v = rs[j];
      v += __shfl_xor(v, 1);
      v += __shfl_xor(v, 2);
      v += __shfl_xor(v, 4);
      v += __shfl_xor(v, 8);
      lrow[j] = lrow[j]*alpha[j] + v;
      o[0][j] *= alpha[j]; o[1][j] *= alpha[j]; o[2][j] *= alpha[j]; o[3][j] *= alpha[j];
    }

    // P -> per-wave LDS (bf16, swizzled) to become MFMA A-operand
    u16* Pw = Ps[wid];
    #pragma unroll
    for (int ni = 0; ni < 4; ++ni)
      #pragma unroll
      for (int j = 0; j < 4; ++j) {
        const int r  = lg*4 + j;
        const int cb = (ni*16 + lr)*2;
        Pw[(r*128 + (cb ^ ((r&7)<<4)))/2] = f2b(s[ni][j]);
      }
    asm volatile("s_waitcnt lgkmcnt(0)" ::: "memory");

    // O += P·V
    #pragma unroll
    for (int ks = 0; ks < 2; ++ks) {
      bf16x8 pf = *(const bf16x8*)(Pw + (lr*128 + ((ks*64 + lg*16) ^ ((lr&7)<<4)))/2);
      #pragma unroll
      for (int df = 0; df < 4; ++df) {
        const int d = df*16 + lr;
        bf16x8 vf = *(const bf16x8*)(Vs + (d*128 + ((ks*64 + lg*16) ^ ((d&7)<<4)))/2);
        o[df] = __builtin_amdgcn_mfma_f32_16x16x32_bf16(pf, vf, o[df], 0, 0, 0);
      }
    }
  }

  const int b = bh / NH, h = bh - b*NH;
  #pragma unroll
  for (int df = 0; df < 4; ++df)
    #pragma unroll
    for (int j = 0; j < 4; ++j) {
      const int n = q0 + wid*16 + lg*4 + j;
      AO[((size_t)(b*SEQ + n))*DIM + h*64 + df*16 + lr] = f2b(o[df][j] / lrow[j]);
    }
}

extern "C" void kernel_launch(void* const* d_in, const int* in_sizes, int n_in,
                              void* d_out, int out_size, void* d_ws, size_t ws_size,
                              hipStream_t stream) {
  const float* x      = (const float*)d_in[0];
  const float* w_qkv  = (const float*)d_in[1];
  const float* b_qkv  = (const float*)d_in[2];
  const float* w_proj = (const float*)d_in[3];
  const float* b_proj = (const float*)d_in[4];
  float* out = (float*)d_out;
  char* ws = (char*)d_ws;

  // ws layout (bytes)
  u16* xb  = (u16*)(ws);                         // 8192*384*2  = 6291456
  u16* wqb = (u16*)(ws + 6291456);               // 1152*384*2  =  884736
  u16* wpb = (u16*)(ws + 7176192);               //  384*384*2  =  294912
  u16* Qb  = (u16*)(ws + 7471104);               // 12*4096*64*2 = 6291456
  u16* Kb  = (u16*)(ws + 13762560);              // same
  u16* Vt  = (u16*)(ws + 20054016);              // same (transposed)
  u16* AO  = (u16*)(ws + 26345472);              // 8192*384*2
  // total 32636928 bytes

  {
    int n8 = (MTOT*DIM)/8;        // 393216
    conv_bf16_kernel<<<dim3((n8+255)/256), dim3(256), 0, stream>>>(x, xb, n8);
  }
  {
    int n8 = (3*DIM*DIM)/8;       // 55296
    conv_bf16_kernel<<<dim3((n8+255)/256), dim3(256), 0, stream>>>(w_qkv, wqb, n8);
  }
  {
    int n8 = (DIM*DIM)/8;         // 18432
    conv_bf16_kernel<<<dim3((n8+255)/256), dim3(256), 0, stream>>>(w_proj, wpb, n8);
  }
  gemm_bt_kernel<0><<<dim3(MTOT/128, (3*DIM)/128), dim3(256), 0, stream>>>(
      xb, wqb, b_qkv, Qb, Kb, Vt, nullptr);
  attn_kernel<<<dim3(SEQ/64, 2*NH), dim3(256), 0, stream>>>(Qb, Kb, Vt, AO);
  gemm_bt_kernel<1><<<dim3(MTOT/128, DIM/128), dim3(256), 0, stream>>>(
      AO, wpb, b_proj, nullptr, nullptr, nullptr, out);
}

// Round 2
// 146.142 us; speedup vs baseline: 1.4988x; 1.4988x over previous
//
#include <hip/hip_runtime.h>
#include <stdint.h>

#define DIM   384
#define NH    6
#define SEQ   4096
#define MTOT  (2*SEQ)

typedef __bf16 bf16x8 __attribute__((ext_vector_type(8)));
typedef float  f32x4  __attribute__((ext_vector_type(4)));
typedef unsigned short u16;
typedef u16 u16x4 __attribute__((ext_vector_type(4)));
typedef u16 u16x8 __attribute__((ext_vector_type(8)));

extern "C" __device__ float __ocml_native_exp2_f32(float);

__device__ __forceinline__ u16 f2b(float f) {
  uint32_t u = __builtin_bit_cast(uint32_t, f);
  u += 0x7fffu + ((u >> 16) & 1u);
  return (u16)(u >> 16);
}

#define GLDS16(gp, lp) \
  __builtin_amdgcn_global_load_lds((const __attribute__((address_space(1))) void*)(gp), \
                                   (__attribute__((address_space(3))) void*)(lp), 16, 0, 0)

// ---------------- fp32 -> bf16 convert, 8 elems/thread ----------------
__global__ void conv_bf16_kernel(const float* __restrict__ in, u16* __restrict__ out, int n8) {
  int i = blockIdx.x * 256 + threadIdx.x;
  if (i >= n8) return;
  float4 a = ((const float4*)in)[2*i];
  float4 b = ((const float4*)in)[2*i+1];
  u16x8 r;
  r[0]=f2b(a.x); r[1]=f2b(a.y); r[2]=f2b(a.z); r[3]=f2b(a.w);
  r[4]=f2b(b.x); r[5]=f2b(b.y); r[6]=f2b(b.z); r[7]=f2b(b.w);
  ((u16x8*)out)[i] = r;
}

// ---------------- GEMM: C[m][f] = sum_c A[m][c]*Bw[f][c] + bias[f] ----------------
// EPI==0: qkv epilogue (scatter Q scaled, K, V transposed). EPI==1: proj -> fp32 Out.
template<int EPI>
__global__ __launch_bounds__(256) void gemm_bt_kernel(
    const u16* __restrict__ A,      // [M][384] bf16 K-contig
    const u16* __restrict__ Bw,     // [F][384] bf16 K-contig
    const float* __restrict__ bias, // [F]
    u16* __restrict__ Qb, u16* __restrict__ Kb, u16* __restrict__ Vt,
    float* __restrict__ Out)
{
  __shared__ u16 As[128*64];
  __shared__ u16 Bs[128*64];
  const int tid = threadIdx.x;
  const int wid = tid >> 6, lane = tid & 63;
  const int lr = lane & 15, lg = lane >> 4;
  const int m0 = blockIdx.x * 128;
  const int f0 = blockIdx.y * 128;
  const int wm = (wid >> 1) * 64, wn = (wid & 1) * 64;
  const f32x4 z4 = {0.f, 0.f, 0.f, 0.f};
  f32x4 acc[4][4];
  #pragma unroll
  for (int i = 0; i < 4; ++i)
    #pragma unroll
    for (int j = 0; j < 4; ++j) acc[i][j] = z4;

  for (int k0 = 0; k0 < 384; k0 += 64) {
    __syncthreads();
    #pragma unroll
    for (int i = 0; i < 4; ++i) {
      const int wb  = i*4096 + wid*1024;
      const int ob  = wb + lane*16;
      const int row = ob >> 7;
      const int lch = ((ob >> 4) & 7) ^ (row & 7);
      GLDS16(A  + (size_t)(m0+row)*384 + k0 + lch*8, As + wb/2);
      GLDS16(Bw + (size_t)(f0+row)*384 + k0 + lch*8, Bs + wb/2);
    }
    __syncthreads();
    #pragma unroll
    for (int ks = 0; ks < 2; ++ks) {
      bf16x8 af[4], bfr[4];
      #pragma unroll
      for (int mi = 0; mi < 4; ++mi) {
        int r = wm + mi*16 + lr;
        af[mi] = *(const bf16x8*)(As + (r*128 + ((ks*64 + lg*16) ^ ((r&7)<<4)))/2);
      }
      #pragma unroll
      for (int ni = 0; ni < 4; ++ni) {
        int r = wn + ni*16 + lr;
        bfr[ni] = *(const bf16x8*)(Bs + (r*128 + ((ks*64 + lg*16) ^ ((r&7)<<4)))/2);
      }
      #pragma unroll
      for (int mi = 0; mi < 4; ++mi)
        #pragma unroll
        for (int ni = 0; ni < 4; ++ni)
          acc[mi][ni] = __builtin_amdgcn_mfma_f32_16x16x32_bf16(af[mi], bfr[ni], acc[mi][ni], 0, 0, 0);
    }
  }

  if (EPI == 0) {
    const int which = f0 / 384;
    #pragma unroll
    for (int ni = 0; ni < 4; ++ni) {
      const int f   = f0 + wn + ni*16 + lr;
      const float bv = bias[f];
      const int rem = f - which*384;
      const int h = rem >> 6, d = rem & 63;
      #pragma unroll
      for (int mi = 0; mi < 4; ++mi) {
        const int m = m0 + wm + mi*16 + lg*4;
        const int b = m >> 12, n = m & 4095;
        const size_t bh = (size_t)(b*NH + h);
        if (which == 0) {
          // Q pre-scaled by (1/sqrt(64)) * log2(e) so attention uses exp2 directly
          #pragma unroll
          for (int j = 0; j < 4; ++j)
            Qb[(bh*SEQ + n + j)*64 + d] = f2b((acc[mi][ni][j] + bv) * 0.1803368801111244f);
        } else if (which == 1) {
          #pragma unroll
          for (int j = 0; j < 4; ++j)
            Kb[(bh*SEQ + n + j)*64 + d] = f2b(acc[mi][ni][j] + bv);
        } else {
          u16x4 pk;
          #pragma unroll
          for (int j = 0; j < 4; ++j) pk[j] = f2b(acc[mi][ni][j] + bv);
          *(u16x4*)(Vt + (bh*64 + d)*SEQ + n) = pk;   // V transposed [bh][d][n]
        }
      }
    }
  } else {
    #pragma unroll
    for (int ni = 0; ni < 4; ++ni) {
      const int f = f0 + wn + ni*16 + lr;
      const float bv = bias[f];
      #pragma unroll
      for (int mi = 0; mi < 4; ++mi) {
        const int m = m0 + wm + mi*16 + lg*4;
        #pragma unroll
        for (int j = 0; j < 4; ++j)
          Out[(size_t)(m+j)*DIM + f] = acc[mi][ni][j] + bv;
      }
    }
  }
}

// ---------------- flash attention (swapped QK^T, in-reg softmax, dbuf K/V) ----------------
// grid (SEQ/64, 12). 4 waves x 16 q-rows. S^T = mfma(Kfrag, Qfrag): per lane q=lane&15,
// 16 keys {16ni+4lg+j}. Softmax in-lane + 2 shfl_xor. P via cvt_pk -> per-wave swizzled LDS.
__global__ __launch_bounds__(256) void attn_kernel(
    const u16* __restrict__ Qb, const u16* __restrict__ Kb, const u16* __restrict__ Vt,
    u16* __restrict__ AO)
{
  __shared__ u16 Ks[2][64*64];
  __shared__ u16 Vs[2][64*64];
  __shared__ u16 Ps[4][16*64];
  const int tid = threadIdx.x;
  const int wid = tid >> 6, lane = tid & 63;
  const int lr = lane & 15, lg = lane >> 4;
  const int q0 = blockIdx.x * 64;
  const int bh = blockIdx.y;
  const u16* Qp = Qb + (size_t)bh*SEQ*64;
  const u16* Kp = Kb + (size_t)bh*SEQ*64;
  const u16* Vp = Vt + (size_t)bh*64*SEQ;

  // Q B-fragments (rows q=lr of the wave tile), held all kernel
  bf16x8 qf[2];
  {
    const u16* qr = Qp + (size_t)(q0 + wid*16 + lr)*64 + lg*8;
    qf[0] = *(const bf16x8*)(qr);
    qf[1] = *(const bf16x8*)(qr + 32);
  }
  const f32x4 z4 = {0.f,0.f,0.f,0.f};
  f32x4 o[4] = {z4, z4, z4, z4};
  float m = -1e30f, l = 0.f;

  auto stage = [&](int buf, int key0) {
    #pragma unroll
    for (int i = 0; i < 2; ++i) {
      const int wb  = i*4096 + wid*1024;
      const int ob  = wb + lane*16;
      const int row = ob >> 7;
      const int lch = ((ob >> 4) & 7) ^ (row & 7);
      GLDS16(Kp + (size_t)(key0+row)*64 + lch*8, &Ks[buf][0] + wb/2);
      GLDS16(Vp + (size_t)row*SEQ + key0 + lch*8, &Vs[buf][0] + wb/2);
    }
  };

  stage(0, 0);
  __syncthreads();
  int cur = 0;

  for (int kt = 0; kt < SEQ/64; ++kt) {
    if (kt + 1 < SEQ/64) stage(cur ^ 1, (kt+1)*64);
    const u16* Kc = &Ks[cur][0];
    const u16* Vc = &Vs[cur][0];

    // S^T = K·Q^T : s[ni][j] = S[key=16ni+4lg+j][q=lr]  (log2-domain, Q pre-scaled)
    f32x4 s[4] = {z4, z4, z4, z4};
    #pragma unroll
    for (int ks = 0; ks < 2; ++ks) {
      #pragma unroll
      for (int ni = 0; ni < 4; ++ni) {
        const int key = ni*16 + lr;
        bf16x8 kf = *(const bf16x8*)(Kc + (key*128 + ((ks*64 + lg*16) ^ ((key&7)<<4)))/2);
        s[ni] = __builtin_amdgcn_mfma_f32_16x16x32_bf16(kf, qf[ks], s[ni], 0, 0, 0);
      }
    }

    // in-lane row max (16 vals) + 2 cross-group shuffles
    float pm = s[0][0];
    #pragma unroll
    for (int ni = 0; ni < 4; ++ni)
      #pragma unroll
      for (int j = 0; j < 4; ++j) pm = fmaxf(pm, s[ni][j]);
    pm = fmaxf(pm, __shfl_xor(pm, 16));
    pm = fmaxf(pm, __shfl_xor(pm, 32));

    // defer-max: only rescale when the running max grew by > 12 (log2 units)
    if (!__all(pm <= m + 12.f)) {
      const float mn = fmaxf(m, pm);
      const float al = __ocml_native_exp2_f32(m - mn);
      m = mn;
      l *= al;
      #pragma unroll
      for (int j = 0; j < 4; ++j) {
        const float alj = __shfl(al, (lane & 48) | (4*lg + j));
        o[0][j] *= alj; o[1][j] *= alj; o[2][j] *= alj; o[3][j] *= alj;
      }
    }

    float rs = 0.f;
    #pragma unroll
    for (int ni = 0; ni < 4; ++ni)
      #pragma unroll
      for (int j = 0; j < 4; ++j) {
        const float p = __ocml_native_exp2_f32(s[ni][j] - m);
        s[ni][j] = p;
        rs += p;
      }
    rs += __shfl_xor(rs, 16);
    rs += __shfl_xor(rs, 32);
    l += rs;

    // P -> per-wave LDS [16 q][64 keys] bf16, st-swizzled; cvt_pk packs key pairs
    u16* Pw = Ps[wid];
    #pragma unroll
    for (int ni = 0; ni < 4; ++ni)
      #pragma unroll
      for (int p = 0; p < 2; ++p) {
        uint32_t c;
        asm("v_cvt_pk_bf16_f32 %0, %1, %2" : "=v"(c) : "v"(s[ni][2*p]), "v"(s[ni][2*p+1]));
        *(uint32_t*)((char*)Pw + lr*128 + ((32*ni + 8*lg + 4*p) ^ ((lr&7)<<4))) = c;
      }
    asm volatile("s_waitcnt lgkmcnt(0)" ::: "memory");

    // O += P·V : o[df] rows q=4lg+j, cols d=df*16+lr (same layout as before)
    #pragma unroll
    for (int ks = 0; ks < 2; ++ks) {
      bf16x8 pf = *(const bf16x8*)((const char*)Pw + lr*128 + ((ks*64 + lg*16) ^ ((lr&7)<<4)));
      #pragma unroll
      for (int df = 0; df < 4; ++df) {
        const int d = df*16 + lr;
        bf16x8 vf = *(const bf16x8*)(Vc + (d*128 + ((ks*64 + lg*16) ^ ((d&7)<<4)))/2);
        o[df] = __builtin_amdgcn_mfma_f32_16x16x32_bf16(pf, vf, o[df], 0, 0, 0);
      }
    }

    __syncthreads();   // drains stage vmcnt + all waves done reading cur
    cur ^= 1;
  }

  const int b = bh / NH, h = bh - b*NH;
  float linv[4];
  #pragma unroll
  for (int j = 0; j < 4; ++j)
    linv[j] = 1.f / __shfl(l, (lane & 48) | (4*lg + j));
  #pragma unroll
  for (int df = 0; df < 4; ++df)
    #pragma unroll
    for (int j = 0; j < 4; ++j) {
      const int n = q0 + wid*16 + lg*4 + j;
      AO[((size_t)(b*SEQ + n))*DIM + h*64 + df*16 + lr] = f2b(o[df][j] * linv[j]);
    }
}

extern "C" void kernel_launch(void* const* d_in, const int* in_sizes, int n_in,
                              void* d_out, int out_size, void* d_ws, size_t ws_size,
                              hipStream_t stream) {
  const float* x      = (const float*)d_in[0];
  const float* w_qkv  = (const float*)d_in[1];
  const float* b_qkv  = (const float*)d_in[2];
  const float* w_proj = (const float*)d_in[3];
  const float* b_proj = (const float*)d_in[4];
  float* out = (float*)d_out;
  char* ws = (char*)d_ws;

  u16* xb  = (u16*)(ws);                         // 8192*384*2
  u16* wqb = (u16*)(ws + 6291456);               // 1152*384*2
  u16* wpb = (u16*)(ws + 7176192);               //  384*384*2
  u16* Qb  = (u16*)(ws + 7471104);               // 12*4096*64*2
  u16* Kb  = (u16*)(ws + 13762560);
  u16* Vt  = (u16*)(ws + 20054016);
  u16* AO  = (u16*)(ws + 26345472);              // 8192*384*2

  {
    int n8 = (MTOT*DIM)/8;
    conv_bf16_kernel<<<dim3((n8+255)/256), dim3(256), 0, stream>>>(x, xb, n8);
  }
  {
    int n8 = (3*DIM*DIM)/8;
    conv_bf16_kernel<<<dim3((n8+255)/256), dim3(256), 0, stream>>>(w_qkv, wqb, n8);
  }
  {
    int n8 = (DIM*DIM)/8;
    conv_bf16_kernel<<<dim3((n8+255)/256), dim3(256), 0, stream>>>(w_proj, wpb, n8);
  }
  gemm_bt_kernel<0><<<dim3(MTOT/128, (3*DIM)/128), dim3(256), 0, stream>>>(
      xb, wqb, b_qkv, Qb, Kb, Vt, nullptr);
  attn_kernel<<<dim3(SEQ/64, 2*NH), dim3(256), 0, stream>>>(Qb, Kb, Vt, AO);
  gemm_bt_kernel<1><<<dim3(MTOT/128, DIM/128), dim3(256), 0, stream>>>(
      AO, wpb, b_proj, nullptr, nullptr, nullptr, out);
}

// Round 3
// 137.647 us; speedup vs baseline: 1.5913x; 1.0617x over previous
//
#include <hip/hip_runtime.h>
#include <stdint.h>

#define DIM   384
#define NH    6
#define SEQ   4096
#define MTOT  (2*SEQ)

typedef __bf16 bf16x8 __attribute__((ext_vector_type(8)));
typedef float  f32x4  __attribute__((ext_vector_type(4)));
typedef unsigned short u16;
typedef u16 u16x4 __attribute__((ext_vector_type(4)));
typedef u16 u16x8 __attribute__((ext_vector_type(8)));
typedef uint32_t u32x4 __attribute__((ext_vector_type(4)));

extern "C" __device__ float __ocml_native_exp2_f32(float);

__device__ __forceinline__ u16 f2b(float f) {
  uint32_t u = __builtin_bit_cast(uint32_t, f);
  u += 0x7fffu + ((u >> 16) & 1u);
  return (u16)(u >> 16);
}

#define GLDS16(gp, lp) \
  __builtin_amdgcn_global_load_lds((const __attribute__((address_space(1))) void*)(gp), \
                                   (__attribute__((address_space(3))) void*)(lp), 16, 0, 0)

// ---------------- fp32 -> bf16 convert, 8 elems/thread ----------------
__global__ void conv_bf16_kernel(const float* __restrict__ in, u16* __restrict__ out, int n8) {
  int i = blockIdx.x * 256 + threadIdx.x;
  if (i >= n8) return;
  float4 a = ((const float4*)in)[2*i];
  float4 b = ((const float4*)in)[2*i+1];
  u16x8 r;
  r[0]=f2b(a.x); r[1]=f2b(a.y); r[2]=f2b(a.z); r[3]=f2b(a.w);
  r[4]=f2b(b.x); r[5]=f2b(b.y); r[6]=f2b(b.z); r[7]=f2b(b.w);
  ((u16x8*)out)[i] = r;
}

// ---------------- GEMM: C[m][f] = sum_c A[m][c]*Bw[f][c] + bias[f] ----------------
template<int EPI>
__global__ __launch_bounds__(256) void gemm_bt_kernel(
    const u16* __restrict__ A,      // [M][384] bf16 K-contig
    const u16* __restrict__ Bw,     // [F][384] bf16 K-contig
    const float* __restrict__ bias, // [F]
    u16* __restrict__ Qb, u16* __restrict__ Kb, u16* __restrict__ Vt,
    float* __restrict__ Out)
{
  __shared__ u16 As[128*64];
  __shared__ u16 Bs[128*64];
  const int tid = threadIdx.x;
  const int wid = tid >> 6, lane = tid & 63;
  const int lr = lane & 15, lg = lane >> 4;
  const int m0 = blockIdx.x * 128;
  const int f0 = blockIdx.y * 128;
  const int wm = (wid >> 1) * 64, wn = (wid & 1) * 64;
  const f32x4 z4 = {0.f, 0.f, 0.f, 0.f};
  f32x4 acc[4][4];
  #pragma unroll
  for (int i = 0; i < 4; ++i)
    #pragma unroll
    for (int j = 0; j < 4; ++j) acc[i][j] = z4;

  for (int k0 = 0; k0 < 384; k0 += 64) {
    __syncthreads();
    #pragma unroll
    for (int i = 0; i < 4; ++i) {
      const int wb  = i*4096 + wid*1024;
      const int ob  = wb + lane*16;
      const int row = ob >> 7;
      const int lch = ((ob >> 4) & 7) ^ (row & 7);
      GLDS16(A  + (size_t)(m0+row)*384 + k0 + lch*8, As + wb/2);
      GLDS16(Bw + (size_t)(f0+row)*384 + k0 + lch*8, Bs + wb/2);
    }
    __syncthreads();
    #pragma unroll
    for (int ks = 0; ks < 2; ++ks) {
      bf16x8 af[4], bfr[4];
      #pragma unroll
      for (int mi = 0; mi < 4; ++mi) {
        int r = wm + mi*16 + lr;
        af[mi] = *(const bf16x8*)(As + (r*128 + ((ks*64 + lg*16) ^ ((r&7)<<4)))/2);
      }
      #pragma unroll
      for (int ni = 0; ni < 4; ++ni) {
        int r = wn + ni*16 + lr;
        bfr[ni] = *(const bf16x8*)(Bs + (r*128 + ((ks*64 + lg*16) ^ ((r&7)<<4)))/2);
      }
      #pragma unroll
      for (int mi = 0; mi < 4; ++mi)
        #pragma unroll
        for (int ni = 0; ni < 4; ++ni)
          acc[mi][ni] = __builtin_amdgcn_mfma_f32_16x16x32_bf16(af[mi], bfr[ni], acc[mi][ni], 0, 0, 0);
    }
  }

  if (EPI == 0) {
    const int which = f0 / 384;
    #pragma unroll
    for (int ni = 0; ni < 4; ++ni) {
      const int f   = f0 + wn + ni*16 + lr;
      const float bv = bias[f];
      const int rem = f - which*384;
      const int h = rem >> 6, d = rem & 63;
      #pragma unroll
      for (int mi = 0; mi < 4; ++mi) {
        const int m = m0 + wm + mi*16 + lg*4;
        const int b = m >> 12, n = m & 4095;
        const size_t bh = (size_t)(b*NH + h);
        if (which == 0) {
          // Q pre-scaled by (1/sqrt(64)) * log2(e) so attention uses exp2 directly
          #pragma unroll
          for (int j = 0; j < 4; ++j)
            Qb[(bh*SEQ + n + j)*64 + d] = f2b((acc[mi][ni][j] + bv) * 0.1803368801111244f);
        } else if (which == 1) {
          #pragma unroll
          for (int j = 0; j < 4; ++j)
            Kb[(bh*SEQ + n + j)*64 + d] = f2b(acc[mi][ni][j] + bv);
        } else {
          u16x4 pk;
          #pragma unroll
          for (int j = 0; j < 4; ++j) pk[j] = f2b(acc[mi][ni][j] + bv);
          *(u16x4*)(Vt + (bh*64 + d)*SEQ + n) = pk;   // V transposed [bh][d][n]
        }
      }
    }
  } else {
    #pragma unroll
    for (int ni = 0; ni < 4; ++ni) {
      const int f = f0 + wn + ni*16 + lr;
      const float bv = bias[f];
      #pragma unroll
      for (int mi = 0; mi < 4; ++mi) {
        const int m = m0 + wm + mi*16 + lg*4;
        #pragma unroll
        for (int j = 0; j < 4; ++j)
          Out[(size_t)(m+j)*DIM + f] = acc[mi][ni][j] + bv;
      }
    }
  }
}

// ---------------- flash attention v3 ----------------
// grid (SEQ/64, 12), 256 threads. Wave wid: qw=wid&1 (q-rows qw*32..+31),
// kh=wid>>1 (key half kh*32..+31 of each 64-key tile). Pair (qw,kh=0)/(qw,kh=1)
// shares q-rows, splits keys; per-iter max merged via LDS, l/O merged at end.
// P stays in registers via cvt_pk + permlane32/16_swap.
__global__ __launch_bounds__(256, 3) void attn_kernel(
    const u16* __restrict__ Qb, const u16* __restrict__ Kb, const u16* __restrict__ Vt,
    u16* __restrict__ AO)
{
  // bytes: KS buf0 @0, KS buf1 @8192, VS buf0 @16384, VS buf1 @24576,
  //        PM @32768 (512B), LB @33280 (256B). Epilogue O-merge reuses @0..16383.
  __shared__ uint32_t smem[8384];
  char* sb = (char*)smem;
  const int tid = threadIdx.x;
  const int wid = tid >> 6, lane = tid & 63;
  const int lr = lane & 15, lg = lane >> 4;
  const int qw = wid & 1, kh = wid >> 1;
  const int q0 = blockIdx.x * 64;
  const int bh = blockIdx.y;
  const u16* Qp = Qb + (size_t)bh*SEQ*64;
  const u16* Kp = Kb + (size_t)bh*SEQ*64;
  const u16* Vp = Vt + (size_t)bh*64*SEQ;

  // Q B-fragments (cols q = q0+qw*32+qc*16+lr), held all kernel
  bf16x8 qf[2][2];
  #pragma unroll
  for (int qc = 0; qc < 2; ++qc)
    #pragma unroll
    for (int ks = 0; ks < 2; ++ks)
      qf[qc][ks] = *(const bf16x8*)(Qp + (size_t)(q0 + qw*32 + qc*16 + lr)*64 + ks*32 + lg*8);

  // hoisted staging bases: thread stages rows r0 (pass0) and r0+32 (pass1)
  const int r0  = tid >> 3;
  const int lch = (tid & 7) ^ (r0 & 7);
  const u16* kS  = Kp + r0*64 + lch*8;
  const u16* vS  = Vp + (size_t)r0*SEQ + lch*8;
  const u16* vS2 = Vp + (size_t)(r0+32)*SEQ + lch*8;
  char* kD = sb + tid*16;
  char* vD = sb + 16384 + tid*16;

  const f32x4 z4 = {0.f,0.f,0.f,0.f};
  f32x4 o[2][4];
  #pragma unroll
  for (int qc = 0; qc < 2; ++qc)
    #pragma unroll
    for (int df = 0; df < 4; ++df) o[qc][df] = z4;
  float m[2] = {-1e30f, -1e30f}, l[2] = {0.f, 0.f};

  // prologue: stage kt=0 into buf0
  GLDS16(kS, kD);  GLDS16(kS + 2048, kD + 4096);
  GLDS16(vS, vD);  GLDS16(vS2, vD + 4096);
  __syncthreads();

  auto body = [&](int bufo, int kt) {
    // issue next-tile staging into the other buffer (drained at end-of-body barrier)
    if (kt < 63) {
      const int nx = kt + 1;
      GLDS16(kS + nx*4096,        kD + (bufo ^ 8192));
      GLDS16(kS + nx*4096 + 2048, kD + (bufo ^ 8192) + 4096);
      GLDS16(vS + nx*64,          vD + (bufo ^ 8192));
      GLDS16(vS2 + nx*64,         vD + (bufo ^ 8192) + 4096);
    }
    // S^T = K·Q^T: s[ni][qc][j] = S[key_loc=16ni+4lg+j][q=16qc+lr] (log2 domain)
    f32x4 s[2][2] = {{z4, z4}, {z4, z4}};
    #pragma unroll
    for (int ks = 0; ks < 2; ++ks)
      #pragma unroll
      for (int ni = 0; ni < 2; ++ni) {
        const int r = kh*32 + ni*16 + lr;
        bf16x8 kf = *(const bf16x8*)(sb + bufo + r*128 + ((ks*64 + lg*16) ^ ((r&7)<<4)));
        #pragma unroll
        for (int qc = 0; qc < 2; ++qc)
          s[ni][qc] = __builtin_amdgcn_mfma_f32_16x16x32_bf16(kf, qf[qc][ks], s[ni][qc], 0, 0, 0);
      }
    // per-half row max (8 in-lane + 2 shfl), then merge across pair via LDS
    float pm[2];
    #pragma unroll
    for (int qc = 0; qc < 2; ++qc) {
      float v = fmaxf(fmaxf(fmaxf(s[0][qc][0], s[0][qc][1]), fmaxf(s[0][qc][2], s[0][qc][3])),
                      fmaxf(fmaxf(s[1][qc][0], s[1][qc][1]), fmaxf(s[1][qc][2], s[1][qc][3])));
      v = fmaxf(v, __shfl_xor(v, 16));
      v = fmaxf(v, __shfl_xor(v, 32));
      pm[qc] = v;
    }
    float* pmf = (float*)(sb + 32768);
    if (lg == 0) { pmf[wid*32 + lr] = pm[0]; pmf[wid*32 + 16 + lr] = pm[1]; }
    asm volatile("s_waitcnt lgkmcnt(0)" ::: "memory");
    __builtin_amdgcn_s_barrier();
    asm volatile("" ::: "memory");
    pm[0] = fmaxf(pm[0], pmf[(wid^2)*32 + lr]);
    pm[1] = fmaxf(pm[1], pmf[(wid^2)*32 + 16 + lr]);
    // defer-max: rescale only when max grew > 12 (log2 units); identical across pair
    if (!__all((pm[0] <= m[0] + 12.f) & (pm[1] <= m[1] + 12.f))) {
      #pragma unroll
      for (int qc = 0; qc < 2; ++qc) {
        const float mn = fmaxf(m[qc], pm[qc]);
        const float al = __ocml_native_exp2_f32(m[qc] - mn);
        m[qc] = mn; l[qc] *= al;
        #pragma unroll
        for (int j = 0; j < 4; ++j) {
          const float alj = __shfl(al, (lane & 48) | (lg*4 + j));
          #pragma unroll
          for (int df = 0; df < 4; ++df) o[qc][df][j] *= alj;
        }
      }
    }
    // exp, sum, pack P to bf16 and redistribute in-register to PV A-fragments
    bf16x8 pf[2];
    #pragma unroll
    for (int qc = 0; qc < 2; ++qc) {
      float rs = 0.f;
      #pragma unroll
      for (int ni = 0; ni < 2; ++ni)
        #pragma unroll
        for (int j = 0; j < 4; ++j) {
          const float p = __ocml_native_exp2_f32(s[ni][qc][j] - m[qc]);
          s[ni][qc][j] = p; rs += p;
        }
      rs += __shfl_xor(rs, 16);
      rs += __shfl_xor(rs, 32);
      l[qc] += rs;
      uint32_t A, B, C, D;
      asm("v_cvt_pk_bf16_f32 %0, %1, %2" : "=v"(A) : "v"(s[0][qc][0]), "v"(s[0][qc][1]));
      asm("v_cvt_pk_bf16_f32 %0, %1, %2" : "=v"(B) : "v"(s[0][qc][2]), "v"(s[0][qc][3]));
      asm("v_cvt_pk_bf16_f32 %0, %1, %2" : "=v"(C) : "v"(s[1][qc][0]), "v"(s[1][qc][1]));
      asm("v_cvt_pk_bf16_f32 %0, %1, %2" : "=v"(D) : "v"(s[1][qc][2]), "v"(s[1][qc][3]));
      // W0 = [A@0,A@2,C@0,C@2], W2 = [A@1,A@3,C@1,C@3] across lg groups (same lr)
      asm("v_permlane32_swap_b32 %0, %1" : "+v"(A), "+v"(C));
      asm("v_permlane16_swap_b32 %0, %1" : "+v"(A), "+v"(C));
      asm("v_permlane32_swap_b32 %0, %1" : "+v"(B), "+v"(D));
      asm("v_permlane16_swap_b32 %0, %1" : "+v"(B), "+v"(D));
      u32x4 wv = {A, B, C, D};
      pf[qc] = __builtin_bit_cast(bf16x8, wv);
    }
    // O += P·V over this wave's key half
    #pragma unroll
    for (int df = 0; df < 4; ++df) {
      const int r = df*16 + lr;
      bf16x8 vf = *(const bf16x8*)(sb + 16384 + bufo + r*128 + ((kh*64 + lg*16) ^ ((r&7)<<4)));
      #pragma unroll
      for (int qc = 0; qc < 2; ++qc)
        o[qc][df] = __builtin_amdgcn_mfma_f32_16x16x32_bf16(pf[qc], vf, o[qc][df], 0, 0, 0);
    }
    // end-of-iter: staging landed + all waves done reading this buffer
    asm volatile("s_waitcnt vmcnt(0) lgkmcnt(0)" ::: "memory");
    __builtin_amdgcn_s_barrier();
    asm volatile("" ::: "memory");
  };

  for (int kt2 = 0; kt2 < 32; ++kt2) {
    body(0,    2*kt2);
    body(8192, 2*kt2 + 1);
  }

  // epilogue: merge O and l across pair partners (kh=1 -> LDS -> kh=0 adds & stores)
  float* obf = (float*)sb;             // 16KB, reuses K staging area
  float* lbf = (float*)(sb + 33280);
  if (kh == 1) {
    #pragma unroll
    for (int qc = 0; qc < 2; ++qc) {
      #pragma unroll
      for (int df = 0; df < 4; ++df)
        #pragma unroll
        for (int j = 0; j < 4; ++j)
          obf[qw*2048 + (qc*16 + lg*4 + j)*64 + df*16 + lr] = o[qc][df][j];
      if (lg == 0) lbf[qw*32 + qc*16 + lr] = l[qc];
    }
  }
  asm volatile("s_waitcnt lgkmcnt(0)" ::: "memory");
  __builtin_amdgcn_s_barrier();
  asm volatile("" ::: "memory");
  if (kh == 0) {
    const int b = bh / NH, h = bh - b*NH;
    #pragma unroll
    for (int qc = 0; qc < 2; ++qc) {
      const float lt = l[qc] + lbf[qw*32 + qc*16 + lr];
      float linv[4];
      #pragma unroll
      for (int j = 0; j < 4; ++j) linv[j] = 1.f / __shfl(lt, (lane & 48) | (lg*4 + j));
      #pragma unroll
      for (int df = 0; df < 4; ++df)
        #pragma unroll
        for (int j = 0; j < 4; ++j) {
          const float v = o[qc][df][j] + obf[qw*2048 + (qc*16 + lg*4 + j)*64 + df*16 + lr];
          const int n = q0 + qw*32 + qc*16 + lg*4 + j;
          AO[((size_t)(b*SEQ + n))*DIM + h*64 + df*16 + lr] = f2b(v * linv[j]);
        }
    }
  }
}

extern "C" void kernel_launch(void* const* d_in, const int* in_sizes, int n_in,
                              void* d_out, int out_size, void* d_ws, size_t ws_size,
                              hipStream_t stream) {
  const float* x      = (const float*)d_in[0];
  const float* w_qkv  = (const float*)d_in[1];
  const float* b_qkv  = (const float*)d_in[2];
  const float* w_proj = (const float*)d_in[3];
  const float* b_proj = (const float*)d_in[4];
  float* out = (float*)d_out;
  char* ws = (char*)d_ws;

  u16* xb  = (u16*)(ws);                         // 8192*384*2
  u16* wqb = (u16*)(ws + 6291456);               // 1152*384*2
  u16* wpb = (u16*)(ws + 7176192);               //  384*384*2
  u16* Qb  = (u16*)(ws + 7471104);               // 12*4096*64*2
  u16* Kb  = (u16*)(ws + 13762560);
  u16* Vt  = (u16*)(ws + 20054016);
  u16* AO  = (u16*)(ws + 26345472);              // 8192*384*2

  {
    int n8 = (MTOT*DIM)/8;
    conv_bf16_kernel<<<dim3((n8+255)/256), dim3(256), 0, stream>>>(x, xb, n8);
  }
  {
    int n8 = (3*DIM*DIM)/8;
    conv_bf16_kernel<<<dim3((n8+255)/256), dim3(256), 0, stream>>>(w_qkv, wqb, n8);
  }
  {
    int n8 = (DIM*DIM)/8;
    conv_bf16_kernel<<<dim3((n8+255)/256), dim3(256), 0, stream>>>(w_proj, wpb, n8);
  }
  gemm_bt_kernel<0><<<dim3(MTOT/128, (3*DIM)/128), dim3(256), 0, stream>>>(
      xb, wqb, b_qkv, Qb, Kb, Vt, nullptr);
  attn_kernel<<<dim3(SEQ/64, 2*NH), dim3(256), 0, stream>>>(Qb, Kb, Vt, AO);
  gemm_bt_kernel<1><<<dim3(MTOT/128, DIM/128), dim3(256), 0, stream>>>(
      AO, wpb, b_proj, nullptr, nullptr, nullptr, out);
}